// Round 2
// baseline (447.984 us; speedup 1.0000x reference)
//
#include <hip/hip_runtime.h>
#include <stdint.h>

#define NROWS 8192   // B*S_LEN = 4*2048
#define INF   4096
#define OUTF  4096
#define RNK   1024

typedef unsigned short u16;
typedef __attribute__((ext_vector_type(8))) short bf16x8;   // 8 bf16 = 4 VGPRs
typedef __attribute__((ext_vector_type(4))) float f32x4;
typedef __attribute__((ext_vector_type(8))) unsigned short u16x8;

__device__ __forceinline__ u16 f32_bf16(float f) {
  union { float f; uint32_t u; } v; v.f = f;
  return (u16)((v.u + 0x7FFF + ((v.u >> 16) & 1)) >> 16);
}

// ---------------- conversion / dequant kernels (memory-bound) ----------------

__global__ __launch_bounds__(256) void convert_x(const float* __restrict__ x,
                                                 u16* __restrict__ o) {
  int t = blockIdx.x * 256 + threadIdx.x;
  int e = t * 8;
  float4 a = *(const float4*)(x + e);
  float4 b = *(const float4*)(x + e + 4);
  u16x8 r;
  r[0] = f32_bf16(a.x); r[1] = f32_bf16(a.y); r[2] = f32_bf16(a.z); r[3] = f32_bf16(a.w);
  r[4] = f32_bf16(b.x); r[5] = f32_bf16(b.y); r[6] = f32_bf16(b.z); r[7] = f32_bf16(b.w);
  *(u16x8*)(o + e) = r;
}

// Vh [RANK][INF]; fold dequantized S into rows of Vh.
__global__ __launch_bounds__(256) void dequant_vh(const int* __restrict__ vh,
                                                  const float* __restrict__ vs,
                                                  const float* __restrict__ vz,
                                                  const int* __restrict__ sd,
                                                  const float* __restrict__ ss,
                                                  const float* __restrict__ sz,
                                                  u16* __restrict__ o) {
  int t = blockIdx.x * 256 + threadIdx.x;
  int e = t * 4;
  int row = e >> 12;              // / INF
  float sval = ((float)sd[row] - sz[0]) * ss[0];
  float sc = vs[0] * sval;
  float zp = vz[0];
  int4 d = *(const int4*)(vh + e);
  ushort4 r;
  r.x = f32_bf16(((float)d.x - zp) * sc);
  r.y = f32_bf16(((float)d.y - zp) * sc);
  r.z = f32_bf16(((float)d.z - zp) * sc);
  r.w = f32_bf16(((float)d.w - zp) * sc);
  *(ushort4*)(o + e) = r;
}

// U [OUTF][RNK]
__global__ __launch_bounds__(256) void dequant_u(const int* __restrict__ ud,
                                                 const float* __restrict__ us,
                                                 const float* __restrict__ uz,
                                                 u16* __restrict__ o) {
  int t = blockIdx.x * 256 + threadIdx.x;
  int e = t * 4;
  float sc = us[0];
  float zp = uz[0];
  int4 d = *(const int4*)(ud + e);
  ushort4 r;
  r.x = f32_bf16(((float)d.x - zp) * sc);
  r.y = f32_bf16(((float)d.y - zp) * sc);
  r.z = f32_bf16(((float)d.z - zp) * sc);
  r.w = f32_bf16(((float)d.w - zp) * sc);
  *(ushort4*)(o + e) = r;
}

// ---------------- bf16 MFMA GEMM, C[m][n] = sum_k A[m][k]*B[n][k] ----------------
// m97-style: 128x128 tile, BK=64, 4 waves (2x2), each wave 4x4 of 16x16x32 MFMA,
// global_load_lds width=16 staging.

__device__ __forceinline__ void gl_lds16(const u16* g, u16* l) {
  __builtin_amdgcn_global_load_lds(
      (const __attribute__((address_space(1))) void*)g,
      (__attribute__((address_space(3))) void*)l, 16, 0, 0);
}

template <bool OUT_BF16, bool ADD_BIAS>
__global__ __launch_bounds__(256) void gemm_bt(const u16* __restrict__ A,
                                               const u16* __restrict__ B,
                                               void* __restrict__ Cv,
                                               const float* __restrict__ bias,
                                               const int N, const int K) {
  constexpr int BM = 128, BN = 128, BK = 64;
  __shared__ __attribute__((aligned(16))) u16 ldsA[BM * BK];
  __shared__ __attribute__((aligned(16))) u16 ldsB[BN * BK];

  const int tid  = threadIdx.x;
  const int lane = tid & 63;
  const int wave = tid >> 6;
  const int bm = blockIdx.y * BM;
  const int bn = blockIdx.x * BN;
  const int wm = (wave >> 1) * 64;
  const int wn = (wave & 1) * 64;

  f32x4 acc[4][4] = {};

  // staging map: thread t loads 16B -> LDS byte offset t*16 (wave-uniform base + lane*16)
  const int srow = tid >> 3;        // 0..31
  const int scol = (tid & 7) * 8;   // 0..56
  const u16* gA = A + (bm + srow) * K + scol;
  const u16* gB = B + (bn + srow) * K + scol;
  u16* lA = ldsA + srow * BK + scol;
  u16* lB = ldsB + srow * BK + scol;

  for (int kt = 0; kt < K; kt += BK) {
#pragma unroll
    for (int i = 0; i < 4; ++i) {
      gl_lds16(gA + i * 32 * K + kt, lA + i * 32 * BK);
      gl_lds16(gB + i * 32 * K + kt, lB + i * 32 * BK);
    }
    __syncthreads();   // compiler emits vmcnt(0) drain before s_barrier

    const int r  = lane & 15;
    const int kq = (lane >> 4) * 8;
#pragma unroll
    for (int ks = 0; ks < BK; ks += 32) {
      bf16x8 af[4], bfr[4];
#pragma unroll
      for (int i = 0; i < 4; ++i)
        af[i] = *(const bf16x8*)(ldsA + (wm + i * 16 + r) * BK + ks + kq);
#pragma unroll
      for (int j = 0; j < 4; ++j)
        bfr[j] = *(const bf16x8*)(ldsB + (wn + j * 16 + r) * BK + ks + kq);
#pragma unroll
      for (int i = 0; i < 4; ++i)
#pragma unroll
        for (int j = 0; j < 4; ++j)
          acc[i][j] = __builtin_amdgcn_mfma_f32_16x16x32_bf16(af[i], bfr[j], acc[i][j], 0, 0, 0);
    }
    __syncthreads();
  }

  // epilogue: C/D layout col = lane&15, row = (lane>>4)*4 + reg  [m89-verified]
  const int col0 = lane & 15;
  const int row0 = (lane >> 4) * 4;
#pragma unroll
  for (int i = 0; i < 4; ++i) {
#pragma unroll
    for (int j = 0; j < 4; ++j) {
      const int gcol = bn + wn + j * 16 + col0;
      float bv = 0.f;
      if (ADD_BIAS) bv = bias[gcol];
#pragma unroll
      for (int rr = 0; rr < 4; ++rr) {
        const int grow = bm + wm + i * 16 + row0 + rr;
        float v = acc[i][j][rr] + bv;
        if (OUT_BF16)
          ((u16*)Cv)[grow * N + gcol] = f32_bf16(v);
        else
          ((float*)Cv)[grow * N + gcol] = v;
      }
    }
  }
}

// ---------------- launch ----------------

extern "C" void kernel_launch(void* const* d_in, const int* in_sizes, int n_in,
                              void* d_out, int out_size, void* d_ws, size_t ws_size,
                              hipStream_t stream) {
  const float* x        = (const float*)d_in[0];
  const int*   U_data   = (const int*)d_in[1];
  const float* U_scale  = (const float*)d_in[2];
  const float* U_zp     = (const float*)d_in[3];
  const int*   S_data   = (const int*)d_in[4];
  const float* S_scale  = (const float*)d_in[5];
  const float* S_zp     = (const float*)d_in[6];
  const int*   Vh_data  = (const int*)d_in[7];
  const float* Vh_scale = (const float*)d_in[8];
  const float* Vh_zp    = (const float*)d_in[9];
  const float* bias     = (const float*)d_in[10];
  float* out = (float*)d_out;

  char* ws = (char*)d_ws;
  u16* xb  = (u16*)ws;                                  // 8192*4096*2  = 64 MiB
  u16* vhb = (u16*)(ws + (size_t)67108864);             // 1024*4096*2  =  8 MiB
  u16* ub  = (u16*)(ws + (size_t)67108864 + 8388608);   // 4096*1024*2  =  8 MiB
  u16* hb  = (u16*)(ws + (size_t)67108864 + 16777216);  // 8192*1024*2  = 16 MiB

  convert_x<<<NROWS * INF / (8 * 256), 256, 0, stream>>>(x, xb);
  dequant_vh<<<RNK * INF / (4 * 256), 256, 0, stream>>>(Vh_data, Vh_scale, Vh_zp,
                                                        S_data, S_scale, S_zp, vhb);
  dequant_u<<<OUTF * RNK / (4 * 256), 256, 0, stream>>>(U_data, U_scale, U_zp, ub);

  // GEMM1: h[8192,1024] = xb[8192,4096] @ vhb[1024,4096]^T   (bf16 out)
  gemm_bt<true, false><<<dim3(RNK / 128, NROWS / 128), 256, 0, stream>>>(
      xb, vhb, (void*)hb, nullptr, RNK, INF);
  // GEMM2: y[8192,4096] = hb[8192,1024] @ ub[4096,1024]^T + bias   (fp32 out)
  gemm_bt<false, true><<<dim3(OUTF / 128, NROWS / 128), 256, 0, stream>>>(
      hb, ub, (void*)out, bias, OUTF, RNK);
}

// Round 3
// 419.934 us; speedup vs baseline: 1.0668x; 1.0668x over previous
//
#include <hip/hip_runtime.h>
#include <stdint.h>

#define NROWS 8192   // B*S_LEN = 4*2048
#define INF   4096
#define OUTF  4096
#define RNK   1024

typedef unsigned short u16;
typedef __attribute__((ext_vector_type(8))) short bf16x8;   // 8 bf16 = 4 VGPRs
typedef __attribute__((ext_vector_type(4))) float f32x4;
typedef __attribute__((ext_vector_type(8))) unsigned short u16x8;

__device__ __forceinline__ u16 f32_bf16(float f) {
  union { float f; uint32_t u; } v; v.f = f;
  return (u16)((v.u + 0x7FFF + ((v.u >> 16) & 1)) >> 16);
}

// ---------------- conversion / dequant kernels (memory-bound) ----------------

__global__ __launch_bounds__(256) void convert_x(const float* __restrict__ x,
                                                 u16* __restrict__ o) {
  int t = blockIdx.x * 256 + threadIdx.x;
  int e = t * 8;
  float4 a = *(const float4*)(x + e);
  float4 b = *(const float4*)(x + e + 4);
  u16x8 r;
  r[0] = f32_bf16(a.x); r[1] = f32_bf16(a.y); r[2] = f32_bf16(a.z); r[3] = f32_bf16(a.w);
  r[4] = f32_bf16(b.x); r[5] = f32_bf16(b.y); r[6] = f32_bf16(b.z); r[7] = f32_bf16(b.w);
  *(u16x8*)(o + e) = r;
}

// Vh [RANK][INF]; fold dequantized S into rows of Vh.
__global__ __launch_bounds__(256) void dequant_vh(const int* __restrict__ vh,
                                                  const float* __restrict__ vs,
                                                  const float* __restrict__ vz,
                                                  const int* __restrict__ sd,
                                                  const float* __restrict__ ss,
                                                  const float* __restrict__ sz,
                                                  u16* __restrict__ o) {
  int t = blockIdx.x * 256 + threadIdx.x;
  int e = t * 4;
  int row = e >> 12;              // / INF
  float sval = ((float)sd[row] - sz[0]) * ss[0];
  float sc = vs[0] * sval;
  float zp = vz[0];
  int4 d = *(const int4*)(vh + e);
  ushort4 r;
  r.x = f32_bf16(((float)d.x - zp) * sc);
  r.y = f32_bf16(((float)d.y - zp) * sc);
  r.z = f32_bf16(((float)d.z - zp) * sc);
  r.w = f32_bf16(((float)d.w - zp) * sc);
  *(ushort4*)(o + e) = r;
}

// U [OUTF][RNK]
__global__ __launch_bounds__(256) void dequant_u(const int* __restrict__ ud,
                                                 const float* __restrict__ us,
                                                 const float* __restrict__ uz,
                                                 u16* __restrict__ o) {
  int t = blockIdx.x * 256 + threadIdx.x;
  int e = t * 4;
  float sc = us[0];
  float zp = uz[0];
  int4 d = *(const int4*)(ud + e);
  ushort4 r;
  r.x = f32_bf16(((float)d.x - zp) * sc);
  r.y = f32_bf16(((float)d.y - zp) * sc);
  r.z = f32_bf16(((float)d.z - zp) * sc);
  r.w = f32_bf16(((float)d.w - zp) * sc);
  *(ushort4*)(o + e) = r;
}

// ---------------- bf16 MFMA GEMM, C[m][n] = sum_k A[m][k]*B[n][k] ----------------
// 128x128 tile, BK=64, 4 waves (2x2), each wave 4x4 of 16x16x32 MFMA,
// global_load_lds width=16 staging.
//
// LDS layout is XOR-swizzled to kill the 16-way bank conflict of a plain
// row-major BK=64 tile: logical column-group cg (8 bf16 = 16 B) of row r is
// stored at physical slot (cg ^ (r & 7)). global_load_lds forces LDS dest =
// wave base + lane*16, so the swizzle is applied by permuting WHICH global
// 16B chunk each lane fetches (same cache-line set -> coalescing preserved).

__device__ __forceinline__ void gl_lds16(const u16* g, u16* l) {
  __builtin_amdgcn_global_load_lds(
      (const __attribute__((address_space(1))) void*)g,
      (__attribute__((address_space(3))) void*)l, 16, 0, 0);
}

template <bool OUT_BF16, bool ADD_BIAS>
__global__ __launch_bounds__(256) void gemm_bt(const u16* __restrict__ A,
                                               const u16* __restrict__ B,
                                               void* __restrict__ Cv,
                                               const float* __restrict__ bias,
                                               const int N, const int K) {
  constexpr int BM = 128, BN = 128, BK = 64;
  __shared__ __attribute__((aligned(16))) u16 ldsA[BM * BK];
  __shared__ __attribute__((aligned(16))) u16 ldsB[BN * BK];

  const int tid  = threadIdx.x;
  const int lane = tid & 63;
  const int wave = tid >> 6;
  const int bm = blockIdx.y * BM;
  const int bn = blockIdx.x * BN;
  const int wm = (wave >> 1) * 64;
  const int wn = (wave & 1) * 64;

  f32x4 acc[4][4] = {};

  // staging: thread t writes LDS physical slot (row = t>>3, cg' = t&7) at
  // byte offset t*16; it must therefore fetch global logical
  // cg = cg' ^ (row & 7).
  const int srow = tid >> 3;                       // 0..31
  const int scol = (((tid & 7) ^ (srow & 7)) * 8); // swizzled global column
  const int lcol = (tid & 7) * 8;                  // physical LDS column
  const u16* gA = A + (bm + srow) * K + scol;
  const u16* gB = B + (bn + srow) * K + scol;
  u16* lA = ldsA + srow * BK + lcol;
  u16* lB = ldsB + srow * BK + lcol;

  for (int kt = 0; kt < K; kt += BK) {
#pragma unroll
    for (int i = 0; i < 4; ++i) {
      // rows srow + 32*i: (row & 7) == (srow & 7), so swizzle term unchanged
      gl_lds16(gA + i * 32 * K + kt, lA + i * 32 * BK);
      gl_lds16(gB + i * 32 * K + kt, lB + i * 32 * BK);
    }
    __syncthreads();

    const int r  = lane & 15;
    const int kq = (lane >> 4) * 8;
#pragma unroll
    for (int ks = 0; ks < BK; ks += 32) {
      // logical column ks+kq -> physical ( ((ks+kq)/8) ^ (r&7) ) * 8
      const int pcol = (((ks + kq) >> 3) ^ (r & 7)) << 3;
      bf16x8 af[4], bfr[4];
#pragma unroll
      for (int i = 0; i < 4; ++i)
        af[i] = *(const bf16x8*)(ldsA + (wm + i * 16 + r) * BK + pcol);
#pragma unroll
      for (int j = 0; j < 4; ++j)
        bfr[j] = *(const bf16x8*)(ldsB + (wn + j * 16 + r) * BK + pcol);
#pragma unroll
      for (int i = 0; i < 4; ++i)
#pragma unroll
        for (int j = 0; j < 4; ++j)
          acc[i][j] = __builtin_amdgcn_mfma_f32_16x16x32_bf16(af[i], bfr[j], acc[i][j], 0, 0, 0);
    }
    __syncthreads();
  }

  // epilogue: C/D layout col = lane&15, row = (lane>>4)*4 + reg  [m89-verified]
  const int col0 = lane & 15;
  const int row0 = (lane >> 4) * 4;
#pragma unroll
  for (int i = 0; i < 4; ++i) {
#pragma unroll
    for (int j = 0; j < 4; ++j) {
      const int gcol = bn + wn + j * 16 + col0;
      float bv = 0.f;
      if (ADD_BIAS) bv = bias[gcol];
#pragma unroll
      for (int rr = 0; rr < 4; ++rr) {
        const int grow = bm + wm + i * 16 + row0 + rr;
        float v = acc[i][j][rr] + bv;
        if (OUT_BF16)
          ((u16*)Cv)[grow * N + gcol] = f32_bf16(v);
        else
          ((float*)Cv)[grow * N + gcol] = v;
      }
    }
  }
}

// ---------------- launch ----------------

extern "C" void kernel_launch(void* const* d_in, const int* in_sizes, int n_in,
                              void* d_out, int out_size, void* d_ws, size_t ws_size,
                              hipStream_t stream) {
  const float* x        = (const float*)d_in[0];
  const int*   U_data   = (const int*)d_in[1];
  const float* U_scale  = (const float*)d_in[2];
  const float* U_zp     = (const float*)d_in[3];
  const int*   S_data   = (const int*)d_in[4];
  const float* S_scale  = (const float*)d_in[5];
  const float* S_zp     = (const float*)d_in[6];
  const int*   Vh_data  = (const int*)d_in[7];
  const float* Vh_scale = (const float*)d_in[8];
  const float* Vh_zp    = (const float*)d_in[9];
  const float* bias     = (const float*)d_in[10];
  float* out = (float*)d_out;

  char* ws = (char*)d_ws;
  u16* xb  = (u16*)ws;                                  // 8192*4096*2  = 64 MiB
  u16* vhb = (u16*)(ws + (size_t)67108864);             // 1024*4096*2  =  8 MiB
  u16* ub  = (u16*)(ws + (size_t)67108864 + 8388608);   // 4096*1024*2  =  8 MiB
  u16* hb  = (u16*)(ws + (size_t)67108864 + 16777216);  // 8192*1024*2  = 16 MiB

  convert_x<<<NROWS * INF / (8 * 256), 256, 0, stream>>>(x, xb);
  dequant_vh<<<RNK * INF / (4 * 256), 256, 0, stream>>>(Vh_data, Vh_scale, Vh_zp,
                                                        S_data, S_scale, S_zp, vhb);
  dequant_u<<<OUTF * RNK / (4 * 256), 256, 0, stream>>>(U_data, U_scale, U_zp, ub);

  // GEMM1: h[8192,1024] = xb[8192,4096] @ vhb[1024,4096]^T   (bf16 out)
  gemm_bt<true, false><<<dim3(RNK / 128, NROWS / 128), 256, 0, stream>>>(
      xb, vhb, (void*)hb, nullptr, RNK, INF);
  // GEMM2: y[8192,4096] = hb[8192,1024] @ ub[4096,1024]^T + bias   (fp32 out)
  gemm_bt<false, true><<<dim3(OUTF / 128, NROWS / 128), 256, 0, stream>>>(
      hb, ub, (void*)out, bias, OUTF, RNK);
}